// Round 10
// baseline (360.489 us; speedup 1.0000x reference)
//
#include <hip/hip_runtime.h>

// B=32, N=36, D=2048, C=4, H=512.  K = 2H = 1024 stacked (coord|feat).
// Out[b,i,d] = max_j sum_k Wcat[k,d] * (crfr[b,j,k] * clfl[b,i,k]) + mm[b,i,d]

typedef __attribute__((ext_vector_type(8))) short short8;
typedef __attribute__((ext_vector_type(4))) short short4v;
typedef __attribute__((ext_vector_type(4))) float f32x4;

__device__ __forceinline__ float bf2f(unsigned short h) {
  return __uint_as_float(((unsigned int)h) << 16);
}
__device__ __forceinline__ unsigned short f2bf(float f) {
  unsigned int u = __float_as_uint(f);
  u += 0x7FFFu + ((u >> 16) & 1u);
  return (unsigned short)(u >> 16);
}
// async global->LDS, 16B per lane; lds dest is wave-uniform base + lane*16
__device__ __forceinline__ void gl2lds16(const void* g, void* l) {
  __builtin_amdgcn_global_load_lds(
      (const __attribute__((address_space(1))) unsigned int*)g,
      (__attribute__((address_space(3))) unsigned int*)l, 16, 0, 0);
}

// ---------------------------------------------------------------------------
// K_prep: bid<2304: coords proj (cl->Lw[:,0:512], cr->Rw[:,0:512]) + mm->bf16.
//         bid>=2304: weights -> MFMA fragment order (WS for K4, WS2 for K3).
__global__ __launch_bounds__(256) void k_prep(
    const float* __restrict__ coords, const float* __restrict__ Wcl,
    const float* __restrict__ Wcr, const float* __restrict__ mm,
    const float* __restrict__ Wcout, const float* __restrict__ Wfout,
    const float* __restrict__ Wfl, const float* __restrict__ Wfr,
    unsigned short* __restrict__ Lw, unsigned short* __restrict__ Rw,
    unsigned short* __restrict__ mmb, unsigned short* __restrict__ WS,
    unsigned short* __restrict__ WS2) {
  const int bid = blockIdx.x;
  if (bid < 2304) {
    int idx = bid * 256 + threadIdx.x;  // 0 .. 1152*512-1
    int row = idx >> 9, h = idx & 511;
    const float* c = coords + row * 4;
    float a0 = c[0], a1 = c[1], a2 = c[2], a3 = c[3];
    float vl = a0 * Wcl[h] + a1 * Wcl[512 + h] + a2 * Wcl[1024 + h] + a3 * Wcl[1536 + h];
    float vr = a0 * Wcr[h] + a1 * Wcr[512 + h] + a2 * Wcr[1024 + h] + a3 * Wcr[1536 + h];
    Lw[(size_t)row * 1024 + h] = f2bf(vl);
    Rw[(size_t)row * 1024 + h] = f2bf(vr);
    float4 m4 = *(const float4*)(mm + (size_t)row * 2048 + h * 4);
    short4v o;
    o[0] = (short)f2bf(m4.x); o[1] = (short)f2bf(m4.y);
    o[2] = (short)f2bf(m4.z); o[3] = (short)f2bf(m4.w);
    *(short4v*)(mmb + (size_t)row * 2048 + h * 4) = o;
  } else {
    int gi = (bid - 2304) * 256 + threadIdx.x;  // 0..524287
    if (gi < 262144) {
      // WS granule gi = ((g2*32+kc)*4+q)*16+n ; elem e: d=g2*16+n, k=kc*32+q*8+e
      int n = gi & 15, qv = (gi >> 4) & 3, kc = (gi >> 6) & 31, g2 = gi >> 11;
      int d = g2 * 16 + n;
      int kbase = kc * 32 + qv * 8;
      const float* src = (kbase < 512) ? (Wcout + (size_t)kbase * 2048 + d)
                                       : (Wfout + (size_t)(kbase - 512) * 2048 + d);
      short8 o;
#pragma unroll
      for (int e = 0; e < 8; ++e) o[e] = (short)f2bf(src[(size_t)e * 2048]);
      *(short8*)(WS + (size_t)gi * 8) = o;
    } else {
      // WS2 granule gj = ((cg*64+kc)*4+q)*16+n ; elem e: col=cg*16+n, dd=kc*32+q*8+e
      int gj = gi - 262144;
      int n = gj & 15, qv = (gj >> 4) & 3, kc = (gj >> 6) & 63, cg = gj >> 12;
      int col = cg * 16 + n;
      int dbase = kc * 32 + qv * 8;
      const float* src = (col < 512) ? (Wfl + (size_t)dbase * 512 + col)
                                     : (Wfr + (size_t)dbase * 512 + (col - 512));
      short8 o;
#pragma unroll
      for (int e = 0; e < 8; ++e) o[e] = (short)f2bf(src[(size_t)e * 512]);
      *(short8*)(WS2 + (size_t)gj * 8) = o;
    }
  }
}

// ---------------------------------------------------------------------------
// K3: feature projection O[row,col] = sum_dd mmb[row,dd]*Wlr[dd,col]
//  col<512 -> fl -> Lw[row][512+col] ; else fr -> Rw[row][col]
__global__ __launch_bounds__(256) void k_proj_feat(
    const unsigned short* __restrict__ mmb, const unsigned short* __restrict__ WS2,
    unsigned short* __restrict__ Lw, unsigned short* __restrict__ Rw) {
  const int tid = threadIdx.x;
  const int lane = tid & 63, w = tid >> 6;
  const int n = lane & 15, q = lane >> 4;
  const int m0 = blockIdx.y * 16;
  const int cg = blockIdx.x * 4 + w;  // 0..63
  const int c0 = cg * 16;

  f32x4 acc = {0.f, 0.f, 0.f, 0.f};
#pragma unroll 4
  for (int kc = 0; kc < 64; ++kc) {
    short8 a = *(const short8*)(mmb + (size_t)(m0 + n) * 2048 + kc * 32 + q * 8);
    short8 b = *(const short8*)(WS2 + (size_t)(cg * 64 + kc) * 512 + lane * 8);
    acc = __builtin_amdgcn_mfma_f32_16x16x32_bf16(a, b, acc, 0, 0, 0);
  }
#pragma unroll
  for (int e = 0; e < 4; ++e) {
    int row = m0 + q * 4 + e;
    int col = c0 + n;
    unsigned short v = f2bf(acc[e]);
    if (col < 512) Lw[(size_t)row * 1024 + 512 + col] = v;
    else           Rw[(size_t)row * 1024 + col] = v;
  }
}

// ---------------------------------------------------------------------------
// K_prod: materialize pair products in MFMA B-fragment order, quad-packed.
// Granule id = (qg*32 + kc)*9 + t ; lane (q,n), elem e: k = kc*32 + q*8 + e.
//   t<8 : group g = qg*4 + (t>>1), col j = (t&1)*16 + n      (full tiles)
//   t=8 : group g = qg*4 + (n>>2), col j = 32 + (n&3)        (shared remainder)
// P = clfl[g,k] * crfr[b,j,k], bf16. Writes perfectly coalesced (idx*16B).
__global__ __launch_bounds__(256) void k_prod(
    const unsigned short* __restrict__ Lw, const unsigned short* __restrict__ Rw,
    unsigned short* __restrict__ Pf) {
  int idx = blockIdx.x * 256 + threadIdx.x;  // 0 .. 5,308,415
  int lane = idx & 63;
  int gran = idx >> 6;          // 0 .. 82943
  int qg = gran / 288;          // 288 granules per quad-group (32 kc * 9 t)
  int rem = gran - qg * 288;
  int kc = rem / 9;
  int t = rem - kc * 9;
  int n = lane & 15, q = lane >> 4;
  int k0 = kc * 32 + q * 8;
  int b = qg / 9;
  int g, j;
  if (t < 8) { g = qg * 4 + (t >> 1); j = (t & 1) * 16 + n; }
  else       { g = qg * 4 + (n >> 2); j = 32 + (n & 3); }
  short8 cl8 = *(const short8*)(Lw + (size_t)g * 1024 + k0);
  short8 cr8 = *(const short8*)(Rw + (size_t)(b * 36 + j) * 1024 + k0);
  short8 p;
#pragma unroll
  for (int e = 0; e < 8; ++e)
    p[e] = (short)f2bf(bf2f((unsigned short)cl8[e]) * bf2f((unsigned short)cr8[e]));
  *(short8*)(Pf + (size_t)idx * 8) = p;
}

// ---------------------------------------------------------------------------
// K4: streaming GEMM + max-over-j + residual, 4-chunk-deep DMA pipeline with
// phase-staggered K order (sum over K is order-invariant).
// Block: 256 thr (4 waves), one quad-group x 256-d tile; wave = 9 tiles x
// r=4 d-granules (acc 144). grid 2304, dt = bx&7 (W-slice XCD-pinned),
// qg = bx>>3 (same-qg dt-blocks co-dispatched -> L3 sharing).
// 8 LDS buffers (72 KB): one barrier per 4 chunks; DMA for super-iter I+1
// issued at top of I -> ~5600 cyc window before the vmcnt(0)+barrier drain.
// Phase = bx&7 staggers each block's chunk order -> desyncs DMA bursts.
__global__ __launch_bounds__(256, 2) void k_pairwise(
    const unsigned short* __restrict__ Pf, const unsigned short* __restrict__ WS,
    const float* __restrict__ mm, float* __restrict__ out) {
  __shared__ __align__(16) unsigned short lB[8][9 * 512];  // 8 x 9 KB

  const int tid = threadIdx.x;
  const int lane = tid & 63, w = tid >> 6;  // w 0..3
  const int n = lane & 15, q = lane >> 4;
  const int bx = blockIdx.x;
  const int dt = bx & 7, qg = bx >> 3;
  const int g0 = qg * 4;
  const int phase = bx & 7;  // stagger start super-iter

  f32x4 acc[9][4];
#pragma unroll
  for (int t = 0; t < 9; ++t)
#pragma unroll
    for (int r = 0; r < 4; ++r) acc[t][r] = (f32x4){0.f, 0.f, 0.f, 0.f};

  // A granule (dgrp=w*4+r, kc): WS + ((dt*16 + dgrp)*32 + kc)*512 + lane*8
  const unsigned short* Abase = WS + (size_t)(dt * 16 + w * 4) * 32 * 512 + lane * 8;
  // B granule (kc, t): Pf + ((qg*32 + kc)*9 + t)*512 + lane*8
  const unsigned short* Bbase = Pf + (size_t)qg * 32 * 9 * 512 + lane * 8;

  // wave w stages tiles {w, 4+w}; wave 0 additionally tile 8.
#define STAGE(kc_, bi_)                                                     \
  do {                                                                      \
    const unsigned short* bn = Bbase + (size_t)((kc_) * 9) * 512;           \
    gl2lds16(bn + (size_t)w * 512, &lB[bi_][w * 512]);                      \
    gl2lds16(bn + (size_t)(4 + w) * 512, &lB[bi_][(4 + w) * 512]);          \
    if (w == 0) gl2lds16(bn + (size_t)8 * 512, &lB[bi_][8 * 512]);          \
  } while (0)

#define ALOAD(dst_, kc_)                                                    \
  do {                                                                      \
    _Pragma("unroll") for (int r = 0; r < 4; ++r)                           \
        dst_[r] = *(const short8*)(Abase + (size_t)(r * 32 + (kc_)) * 512); \
  } while (0)

  short8 aR[4], aN[4];
  // prologue: stage super-iter 0 (4 chunks), load A for its first chunk
  const int ks0 = phase & 7;
#pragma unroll
  for (int c = 0; c < 4; ++c) STAGE(ks0 * 4 + c, c);
  ALOAD(aR, ks0 * 4);
  __syncthreads();  // drain -> lB[0..3] ready

#pragma unroll 1
  for (int si = 0; si < 8; ++si) {
    const int bsel = (si & 1) * 4;
    const int kcur = ((si + phase) & 7) * 4;
    const int knext = ((si + 1 + phase) & 7) * 4;
    if (si < 7) {  // stage next super-iter into the other buffer quad
#pragma unroll
      for (int c = 0; c < 4; ++c) STAGE(knext + c, (bsel ^ 4) + c);
    }
#pragma unroll
    for (int c = 0; c < 4; ++c) {
      // prefetch A for the following chunk
      const int ka = (c < 3) ? (kcur + c + 1) : ((si < 7) ? knext : kcur);
      ALOAD(aN, ka);
      short8 bb[9];
#pragma unroll
      for (int t = 0; t < 9; ++t)
        bb[t] = *(const short8*)(&lB[bsel + c][t * 512 + lane * 8]);
#pragma unroll
      for (int t = 0; t < 9; ++t)
#pragma unroll
        for (int r = 0; r < 4; ++r)
          acc[t][r] = __builtin_amdgcn_mfma_f32_16x16x32_bf16(aR[r], bb[t], acc[t][r], 0, 0, 0);
#pragma unroll
      for (int r = 0; r < 4; ++r) aR[r] = aN[r];
    }
    __syncthreads();  // drains next super-iter's DMA (issued ~5600 cyc earlier)
  }
#undef STAGE
#undef ALOAD

  // epilogue: per (r,e,ii): max over full tiles 2ii,2ii+1 (j=n, 16+n) and the
  // shared tile's lanes with n>>2==ii (j=32+(n&3)); xor-reduce over 16 n-lanes.
#pragma unroll
  for (int r = 0; r < 4; ++r) {
#pragma unroll
    for (int e = 0; e < 4; ++e) {
      float vs = acc[8][r][e];
#pragma unroll
      for (int ii = 0; ii < 4; ++ii) {
        float v = fmaxf(acc[ii * 2][r][e], acc[ii * 2 + 1][r][e]);
        v = fmaxf(v, ((n >> 2) == ii) ? vs : -1e30f);
#pragma unroll
        for (int s = 1; s < 16; s <<= 1) v = fmaxf(v, __shfl_xor(v, s, 64));
        if (n == 0) {
          int d = dt * 256 + (w * 4 + r) * 16 + q * 4 + e;
          size_t o = (size_t)(g0 + ii) * 2048 + d;
          out[o] = v + mm[o];
        }
      }
    }
  }
}

// ---------------------------------------------------------------------------
extern "C" void kernel_launch(void* const* d_in, const int* in_sizes, int n_in,
                              void* d_out, int out_size, void* d_ws, size_t ws_size,
                              hipStream_t stream) {
  const float* mm     = (const float*)d_in[0];
  const float* coords = (const float*)d_in[1];
  const float* Wcl    = (const float*)d_in[2];
  const float* Wcr    = (const float*)d_in[3];
  const float* Wcout  = (const float*)d_in[4];
  const float* Wfl    = (const float*)d_in[5];
  const float* Wfr    = (const float*)d_in[6];
  const float* Wfout  = (const float*)d_in[7];
  float* out = (float*)d_out;

  // workspace (bf16 shorts), ~103 MB total
  unsigned short* Lw  = (unsigned short*)d_ws;   // [1152][1024]  cl | fl
  unsigned short* Rw  = Lw + 1152 * 1024;        // [1152][1024]  cr | fr
  unsigned short* WS  = Rw + 1152 * 1024;        // 262144 granules x 8 (Wcat^T frag)
  unsigned short* WS2 = WS + (size_t)262144 * 8; // 262144 granules x 8 ((Wfl|Wfr)^T frag)
  unsigned short* mmb = WS2 + (size_t)262144 * 8;// [1152][2048]  mm in bf16
  unsigned short* Pf  = mmb + (size_t)1152 * 2048; // 82944 granules x 512 (products, 85MB)

  k_prep<<<2304 + 2048, 256, 0, stream>>>(coords, Wcl, Wcr, mm, Wcout, Wfout,
                                          Wfl, Wfr, Lw, Rw, mmb, WS, WS2);
  k_proj_feat<<<dim3(16, 72), 256, 0, stream>>>(mmb, WS2, Lw, Rw);
  k_prod<<<20736, 256, 0, stream>>>(Lw, Rw, Pf);
  k_pairwise<<<2304, 256, 0, stream>>>(Pf, WS, mm, out);
}